// Round 16
// baseline (171.297 us; speedup 1.0000x reference)
//
#include <hip/hip_runtime.h>
#include <hip/hip_bf16.h>

#define DD 128
#define CAP 16          // one 64B cache line per row
#define OVF_MAX 8192

typedef __bf16 bf16x8v __attribute__((ext_vector_type(8)));
typedef float  f32x4   __attribute__((ext_vector_type(4)));

__device__ inline unsigned short f2bf(float f) {
    unsigned u = __builtin_bit_cast(unsigned, f);
    unsigned r = (u + 0x7fffu + ((u >> 16) & 1u)) >> 16;
    return (unsigned short)r;
}
__device__ inline float bflo2f(unsigned p) { return __builtin_bit_cast(float, p << 16); }
__device__ inline float bfhi2f(unsigned p) { return __builtin_bit_cast(float, p & 0xffff0000u); }
__device__ inline float rl_f(int v, int i) {
    return __builtin_bit_cast(float, __builtin_amdgcn_readlane(v, i));
}

// ---- zero fillc[N] + ovfcnt ----
__global__ __launch_bounds__(256) void k_zero(int* __restrict__ a, int N) {
    int i = blockIdx.x * 256 + threadIdx.x;
    int stride = gridDim.x * 256;
    for (; i <= N; i += stride) a[i] = 0;   // N fillc + 1 ovfcnt (a[N])
}

// ---- padded fill (no scan, no hist) + fuse1 (Wf = Wv@Wo, bfo = bv@Wo+bo) ----
__global__ __launch_bounds__(256) void k_fill_fuse1(const int* __restrict__ src, const int* __restrict__ dst,
                                                    int* __restrict__ fillc, int* __restrict__ srcp,
                                                    int* __restrict__ ovfcnt, int2* __restrict__ ovf,
                                                    int E, int N, int EB,
                                                    const float* __restrict__ Wv, const float* __restrict__ Wo,
                                                    const float* __restrict__ bv, const float* __restrict__ bo,
                                                    float* __restrict__ Wf, float* __restrict__ bfo) {
    if ((int)blockIdx.x < EB) {
        int e = blockIdx.x * 256 + threadIdx.x;
        if (e >= E) return;
        int s = src[e], d = dst[e];
        if ((unsigned)s >= (unsigned)N || (unsigned)d >= (unsigned)N) return;
        int pos = atomicAdd(&fillc[d], 1);
        if (pos < CAP) srcp[(size_t)d * CAP + pos] = s;
        else {
            int op = atomicAdd(ovfcnt, 1);
            if (op < OVF_MAX) ovf[op] = make_int2(s, d);
        }
    } else {
        int gid = (blockIdx.x - EB) * 256 + threadIdx.x;
        if (gid >= (DD + 1) * DD) return;
        int i = gid >> 7, j = gid & (DD - 1);
        if (i < DD) {
            float acc = 0.f;
            for (int k = 0; k < DD; ++k) acc = fmaf(Wv[i * DD + k], Wo[k * DD + j], acc);
            Wf[i * DD + j] = acc;
        } else {
            float acc = bo[j];
            for (int k = 0; k < DD; ++k) acc = fmaf(bv[k], Wo[k * DD + j], acc);
            bfo[j] = acc;
        }
    }
}

// ---- dinv from fillc + weight prep (W2f^T bf16, bf2, Wt1) ----
__global__ __launch_bounds__(256) void k_dinv_wprep(const int* __restrict__ fillc, float* __restrict__ dinv,
                                                    int N, int nb,
                                                    const float* __restrict__ W2, const float* __restrict__ Wf,
                                                    const float* __restrict__ b2, const float* __restrict__ bfo,
                                                    unsigned short* __restrict__ W2ft, float* __restrict__ bf2,
                                                    const float* __restrict__ W1, unsigned short* __restrict__ Wt1) {
    if ((int)blockIdx.x < nb) {
        int n = blockIdx.x * 256 + threadIdx.x;
        if (n < N) dinv[n] = rsqrtf(1.0f + (float)fillc[n]);
    } else {
        int blk = blockIdx.x - nb;
        if (blk < 65) {
            int gid = blk * 256 + threadIdx.x;
            if (gid >= (DD + 1) * DD) return;
            int i = gid >> 7, j = gid & (DD - 1);
            if (i < DD) {
                float acc = 0.f;
                for (int k = 0; k < DD; ++k) acc = fmaf(W2[i * DD + k], Wf[k * DD + j], acc);
                W2ft[j * DD + i] = f2bf(acc);       // transposed bf16
            } else {
                float acc = bfo[j];
                for (int k = 0; k < DD; ++k) acc = fmaf(b2[k], Wf[k * DD + j], acc);
                bf2[j] = acc;
            }
        } else {
            int gid = (blk - 65) * 256 + threadIdx.x;   // 16384
            int k = gid >> 7, n = gid & 127;
            Wt1[n * DD + k] = f2bf(W1[k * DD + n]);
        }
    }
}

// ---- MFMA GEMM: Cb[M x 128] bf16 = A[M x 128] @ Wt^T ----
// B fragments preloaded in registers; no LDS, no syncthreads. Grid 512 (R9-proven).
// Layouts (m89/m91): a/b frag: idx=l&15, k=(l>>4)*8+j; D: col=l&15, row=(l>>4)*4+reg.
template<int AF32>
__global__ __launch_bounds__(256, 2) void k_gemm_mfma(const void* __restrict__ Av,
                                                      const unsigned short* __restrict__ Wt,
                                                      unsigned short* __restrict__ Cb, int M) {
    int w  = threadIdx.x >> 6;
    int l  = threadIdx.x & 63;
    int lr = l & 15, lg = l >> 4;

    bf16x8v bfr[8][4];
    #pragma unroll
    for (int nt = 0; nt < 8; ++nt)
        #pragma unroll
        for (int kk = 0; kk < 4; ++kk)
            bfr[nt][kk] = *reinterpret_cast<const bf16x8v*>(Wt + (nt * 16 + lr) * DD + kk * 32 + lg * 8);

    int tiles = (M + 63) >> 6;
    for (int t = blockIdx.x; t < tiles; t += gridDim.x) {
        int m0 = t * 64 + w * 16;
        int row = m0 + lr;
        int rowc = row < M ? row : (M - 1);

        bf16x8v af[4];
        if (AF32) {
            const float* Af = (const float*)Av;
            #pragma unroll
            for (int kk = 0; kk < 4; ++kk) {
                const float* p = Af + (size_t)rowc * DD + kk * 32 + lg * 8;
                float4 u0 = *reinterpret_cast<const float4*>(p);
                float4 u1 = *reinterpret_cast<const float4*>(p + 4);
                af[kk][0] = (__bf16)u0.x; af[kk][1] = (__bf16)u0.y;
                af[kk][2] = (__bf16)u0.z; af[kk][3] = (__bf16)u0.w;
                af[kk][4] = (__bf16)u1.x; af[kk][5] = (__bf16)u1.y;
                af[kk][6] = (__bf16)u1.z; af[kk][7] = (__bf16)u1.w;
            }
        } else {
            const unsigned short* Ab = (const unsigned short*)Av;
            #pragma unroll
            for (int kk = 0; kk < 4; ++kk)
                af[kk] = *reinterpret_cast<const bf16x8v*>(Ab + (size_t)rowc * DD + kk * 32 + lg * 8);
        }

        f32x4 acc[8] = {};
        #pragma unroll
        for (int kk = 0; kk < 4; ++kk)
            #pragma unroll
            for (int nt = 0; nt < 8; ++nt)
                acc[nt] = __builtin_amdgcn_mfma_f32_16x16x32_bf16(af[kk], bfr[nt][kk], acc[nt], 0, 0, 0);

        #pragma unroll
        for (int nt = 0; nt < 8; ++nt)
            #pragma unroll
            for (int r = 0; r < 4; ++r) {
                int rr = m0 + lg * 4 + r;
                if (rr < M) Cb[(size_t)rr * DD + nt * 16 + lr] = f2bf(acc[nt][r]);
            }
    }
}

// ---- padded-CSR gather: 4 rows/wave, all loads upfront, dinv[d] factored out ----
// acc = sum_e dinv[src]*h[src]; out = dinv[d]*acc + dinv[d]^2*h[d] + bias
template<int OUTF32, int RELU>
__global__ __launch_bounds__(256) void k_gather_pad(const int* __restrict__ fillc, const int* __restrict__ srcp,
                                                    const float* __restrict__ dinv, const unsigned* __restrict__ h32,
                                                    const float* __restrict__ bias, void* __restrict__ outp,
                                                    int N, const int* __restrict__ ovfcnt, const int2* __restrict__ ovf) {
    int l = threadIdx.x & 63;
    int g = blockIdx.x * 4 + (threadIdx.x >> 6);   // 4-row group id
    int m0 = g * 4;
    if (m0 >= N) return;
    float2 bb = reinterpret_cast<const float2*>(bias)[l];

    // degrees for the 4 rows (lanes 0..3)
    int fcidx = m0 + l; if (fcidx >= N) fcidx = N - 1;
    int fc = (l < 4) ? fillc[fcidx] : 0;

    int deg[4], c[4], sv[4], wvb[4];
    #pragma unroll
    for (int r = 0; r < 4; ++r) {
        deg[r] = __builtin_amdgcn_readlane(fc, r);
        int cc = deg[r] > CAP ? CAP : deg[r];
        c[r] = cc;
        int row = (m0 + r < N) ? (m0 + r) : (N - 1);
        sv[r] = (cc > 0) ? srcp[(size_t)row * CAP + (l < cc ? l : cc - 1)] : 0;
    }
    #pragma unroll
    for (int r = 0; r < 4; ++r)
        wvb[r] = __builtin_bit_cast(int, dinv[sv[r]]);   // per-lane gather of dinv[src]

    // upfront: 32 row loads + 4 self loads in flight before any consumption
    unsigned p[4][8]; float w[4][8];
    #pragma unroll
    for (int r = 0; r < 4; ++r) {
        int f = c[r] < 8 ? c[r] : 8;
        #pragma unroll
        for (int q = 0; q < 8; ++q) {
            int i = (q < f) ? q : (f > 0 ? f - 1 : 0);
            int s = __builtin_amdgcn_readlane(sv[r], i);
            p[r][q] = h32[(size_t)s * 64 + l];
            w[r][q] = (q < f) ? rl_f(wvb[r], i) : 0.f;
        }
    }
    unsigned ps[4];
    #pragma unroll
    for (int r = 0; r < 4; ++r) {
        int n = m0 + r; int nc = n < N ? n : N - 1;
        ps[r] = h32[(size_t)nc * 64 + l];
    }

    float ax[4] = {0.f, 0.f, 0.f, 0.f}, ay[4] = {0.f, 0.f, 0.f, 0.f};
    #pragma unroll
    for (int r = 0; r < 4; ++r)
        #pragma unroll
        for (int q = 0; q < 8; ++q) {
            ax[r] = fmaf(w[r][q], bflo2f(p[r][q]), ax[r]);
            ay[r] = fmaf(w[r][q], bfhi2f(p[r][q]), ay[r]);
        }

    // deg in (8,16]: remaining batch within the chunk registers
    #pragma unroll
    for (int r = 0; r < 4; ++r) {
        for (int i = 8; i < c[r]; i += 8) {
            #pragma unroll
            for (int q = 0; q < 8; ++q) {
                int ii = (i + q < c[r]) ? i + q : c[r] - 1;
                int s = __builtin_amdgcn_readlane(sv[r], ii);
                unsigned pp = h32[(size_t)s * 64 + l];
                float wq = (i + q < c[r]) ? rl_f(wvb[r], ii) : 0.f;
                ax[r] = fmaf(wq, bflo2f(pp), ax[r]);
                ay[r] = fmaf(wq, bfhi2f(pp), ay[r]);
            }
        }
    }

    // overflow (deg > CAP): exact fallback, ~25 rows / ~40 edges expected
    int anyovf = 0;
    #pragma unroll
    for (int r = 0; r < 4; ++r) anyovf |= (deg[r] > CAP) ? 1 : 0;
    if (anyovf) {
        int oc = *ovfcnt; if (oc > OVF_MAX) oc = OVF_MAX;
        for (int i = 0; i < oc; ++i) {
            int2 e = ovf[i];
            #pragma unroll
            for (int r = 0; r < 4; ++r) {
                if (deg[r] > CAP && e.y == m0 + r) {
                    float wq = dinv[e.x];
                    unsigned pp = h32[(size_t)e.x * 64 + l];
                    ax[r] = fmaf(wq, bflo2f(pp), ax[r]);
                    ay[r] = fmaf(wq, bfhi2f(pp), ay[r]);
                }
            }
        }
    }

    // epilogue: out = di*acc + di^2*self + bias
    #pragma unroll
    for (int r = 0; r < 4; ++r) {
        int n = m0 + r;
        if (n < N) {
            float di = rsqrtf(1.0f + (float)deg[r]);
            float di2 = di * di;
            float ox = fmaf(di2, bflo2f(ps[r]), di * ax[r]) + bb.x;
            float oy = fmaf(di2, bfhi2f(ps[r]), di * ay[r]) + bb.y;
            if (RELU) { ox = fmaxf(ox, 0.f); oy = fmaxf(oy, 0.f); }
            if (OUTF32) {
                reinterpret_cast<float2*>(outp)[(size_t)n * 64 + l] = make_float2(ox, oy);
            } else {
                unsigned po = (unsigned)f2bf(ox) | ((unsigned)f2bf(oy) << 16);
                reinterpret_cast<unsigned*>(outp)[(size_t)n * 64 + l] = po;
            }
        }
    }
}

extern "C" void kernel_launch(void* const* d_in, const int* in_sizes, int n_in,
                              void* d_out, int out_size, void* d_ws, size_t ws_size,
                              hipStream_t stream) {
    const float* x  = (const float*)d_in[0];
    const int*   ei = (const int*)d_in[1];
    const float* W1 = (const float*)d_in[2];
    const float* b1 = (const float*)d_in[3];
    const float* W2 = (const float*)d_in[4];
    const float* b2 = (const float*)d_in[5];
    // Wq/bq/Wk/bk (6..9) dead: softmax over seq_len=1 is identity.
    const float* Wv = (const float*)d_in[10];
    const float* bv = (const float*)d_in[11];
    const float* Wo = (const float*)d_in[12];
    const float* bo = (const float*)d_in[13];
    int N = in_sizes[0] / DD;
    int E = in_sizes[1] / 2;
    const int* src = ei;
    const int* dst = ei + E;
    float* out = (float*)d_out;

    unsigned* hA  = (unsigned*)d_ws;                  // N*64 u32 (bf16 GEMM out)
    unsigned* h1  = hA + (size_t)N * 64;              // N*64 u32 (bf16 h1)
    float* dinv   = (float*)(h1 + (size_t)N * 64);    // N
    float* Wf     = dinv + N;                         // 128*128 f32
    float* bfo    = Wf + DD * DD;                     // 128
    float* bf2    = bfo + DD;                         // 128
    unsigned short* Wt1  = (unsigned short*)(bf2 + DD);   // 128*128 bf16
    unsigned short* W2ft = Wt1 + DD * DD;                 // 128*128 bf16
    int* fillc  = (int*)(W2ft + DD * DD);             // N (+1 for ovfcnt)
    int* ovfcnt = fillc + N;                          // 1
    int2* ovf   = (int2*)(((uintptr_t)(ovfcnt + 1) + 63) & ~(uintptr_t)63);   // OVF_MAX
    int* srcp   = (int*)(((uintptr_t)(ovf + OVF_MAX) + 63) & ~(uintptr_t)63); // N*CAP, 64B-aligned

    int nb = (N + 255) / 256;
    int EB = (E + 255) / 256;

    // D1: zero fillc + ovfcnt
    k_zero<<<512, 256, 0, stream>>>(fillc, N);
    // D2: padded CSR fill (line-aligned rows) + MHA weight fold
    k_fill_fuse1<<<EB + 129, 256, 0, stream>>>(src, dst, fillc, srcp, ovfcnt, ovf, E, N, EB,
                                               Wv, Wo, bv, bo, Wf, bfo);
    // D3: dinv + weight transposes (needs fillc, Wf from D2)
    k_dinv_wprep<<<nb + 129, 256, 0, stream>>>(fillc, dinv, N, nb,
                                               W2, Wf, b2, bfo, W2ft, bf2, W1, Wt1);
    // D4: layer-1 GEMM: hA = bf16(x @ W1)
    k_gemm_mfma<1><<<512, 256, 0, stream>>>(x, Wt1, (unsigned short*)hA, N);
    int nwaves = (N + 3) / 4;
    int gb = (nwaves + 3) / 4;   // 4 waves/block, 4 rows/wave
    // D5: gather layer 1 -> h1 (bf16, relu, +b1)
    k_gather_pad<0, 1><<<gb, 256, 0, stream>>>(fillc, srcp, dinv, hA, b1, h1, N, ovfcnt, ovf);
    // D6: layer-2 GEMM (W2·Wv·Wo folded): hA = bf16(h1 @ W2f)
    k_gemm_mfma<0><<<512, 256, 0, stream>>>(h1, W2ft, (unsigned short*)hA, N);
    // D7: gather layer 2 -> out (f32, +bf2)
    k_gather_pad<1, 0><<<gb, 256, 0, stream>>>(fillc, srcp, dinv, hA, bf2, out, N, ovfcnt, ovf);
}

// Round 17
// 165.818 us; speedup vs baseline: 1.0330x; 1.0330x over previous
//
#include <hip/hip_runtime.h>
#include <hip/hip_bf16.h>

#define DD 128
#define CAP 16          // one 64B cache line per row
#define OVF_MAX 8192
#define ECHUNK 2048     // edges per fill block

typedef __bf16 bf16x8v __attribute__((ext_vector_type(8)));
typedef float  f32x4   __attribute__((ext_vector_type(4)));

__device__ inline unsigned short f2bf(float f) {
    unsigned u = __builtin_bit_cast(unsigned, f);
    unsigned r = (u + 0x7fffu + ((u >> 16) & 1u)) >> 16;
    return (unsigned short)r;
}
__device__ inline float bflo2f(unsigned p) { return __builtin_bit_cast(float, p << 16); }
__device__ inline float bfhi2f(unsigned p) { return __builtin_bit_cast(float, p & 0xffff0000u); }
__device__ inline float rl_f(int v, int i) {
    return __builtin_bit_cast(float, __builtin_amdgcn_readlane(v, i));
}

// ---- zero fillc[N] + ovfcnt ----
__global__ __launch_bounds__(256) void k_zero(int* __restrict__ a, int N) {
    int i = blockIdx.x * 256 + threadIdx.x;
    int stride = gridDim.x * 256;
    for (; i <= N; i += stride) a[i] = 0;   // N fillc + 1 ovfcnt (a[N])
}

// ---- XCD-local padded fill + fuse1 (Wf = Wv@Wo, bfo = bv@Wo+bo) ----
// Fill blocks: bin = blockIdx%8 (assumed == XCD via HW round-robin); each block
// scans one edge chunk and keeps only dst in its bin -> fillc/srcp lines for a
// bin are touched by ONE XCD only -> atomics+stores stay L2-local.
__global__ __launch_bounds__(256) void k_fill_fuse1(const int* __restrict__ src, const int* __restrict__ dst,
                                                    int* __restrict__ fillc, int* __restrict__ srcp,
                                                    int* __restrict__ ovfcnt, int2* __restrict__ ovf,
                                                    int E, int N, int FB,
                                                    const float* __restrict__ Wv, const float* __restrict__ Wo,
                                                    const float* __restrict__ bv, const float* __restrict__ bo,
                                                    float* __restrict__ Wf, float* __restrict__ bfo) {
    if ((int)blockIdx.x < FB) {
        int bin   = blockIdx.x & 7;
        int chunk = blockIdx.x >> 3;
        int binsz = (N + 7) / 8;
        int lo = bin * binsz;
        int hi = lo + binsz; if (hi > N) hi = N;
        int base = chunk * ECHUNK + threadIdx.x;
        #pragma unroll
        for (int i = 0; i < ECHUNK / 256; ++i) {
            int e = base + i * 256;
            if (e < E) {
                int d = dst[e];
                if (d >= lo && d < hi) {
                    int s = src[e];
                    if ((unsigned)s < (unsigned)N) {
                        int pos = atomicAdd(&fillc[d], 1);
                        if (pos < CAP) srcp[(size_t)d * CAP + pos] = s;
                        else {
                            int op = atomicAdd(ovfcnt, 1);
                            if (op < OVF_MAX) ovf[op] = make_int2(s, d);
                        }
                    }
                }
            }
        }
    } else {
        int gid = (blockIdx.x - FB) * 256 + threadIdx.x;
        if (gid >= (DD + 1) * DD) return;
        int i = gid >> 7, j = gid & (DD - 1);
        if (i < DD) {
            float acc = 0.f;
            for (int k = 0; k < DD; ++k) acc = fmaf(Wv[i * DD + k], Wo[k * DD + j], acc);
            Wf[i * DD + j] = acc;
        } else {
            float acc = bo[j];
            for (int k = 0; k < DD; ++k) acc = fmaf(bv[k], Wo[k * DD + j], acc);
            bfo[j] = acc;
        }
    }
}

// ---- dinv from fillc + weight prep (W2f^T bf16, bf2, Wt1) ----
__global__ __launch_bounds__(256) void k_dinv_wprep(const int* __restrict__ fillc, float* __restrict__ dinv,
                                                    int N, int nb,
                                                    const float* __restrict__ W2, const float* __restrict__ Wf,
                                                    const float* __restrict__ b2, const float* __restrict__ bfo,
                                                    unsigned short* __restrict__ W2ft, float* __restrict__ bf2,
                                                    const float* __restrict__ W1, unsigned short* __restrict__ Wt1) {
    if ((int)blockIdx.x < nb) {
        int n = blockIdx.x * 256 + threadIdx.x;
        if (n < N) dinv[n] = rsqrtf(1.0f + (float)fillc[n]);
    } else {
        int blk = blockIdx.x - nb;
        if (blk < 65) {
            int gid = blk * 256 + threadIdx.x;
            if (gid >= (DD + 1) * DD) return;
            int i = gid >> 7, j = gid & (DD - 1);
            if (i < DD) {
                float acc = 0.f;
                for (int k = 0; k < DD; ++k) acc = fmaf(W2[i * DD + k], Wf[k * DD + j], acc);
                W2ft[j * DD + i] = f2bf(acc);       // transposed bf16
            } else {
                float acc = bfo[j];
                for (int k = 0; k < DD; ++k) acc = fmaf(b2[k], Wf[k * DD + j], acc);
                bf2[j] = acc;
            }
        } else {
            int gid = (blk - 65) * 256 + threadIdx.x;   // 16384
            int k = gid >> 7, n = gid & 127;
            Wt1[n * DD + k] = f2bf(W1[k * DD + n]);
        }
    }
}

// ---- MFMA GEMM: Cb[M x 128] bf16 = A[M x 128] @ Wt^T ----
// B fragments preloaded in registers; no LDS, no syncthreads. Grid 512 (R9-proven).
// Layouts (m89/m91): a/b frag: idx=l&15, k=(l>>4)*8+j; D: col=l&15, row=(l>>4)*4+reg.
template<int AF32>
__global__ __launch_bounds__(256, 2) void k_gemm_mfma(const void* __restrict__ Av,
                                                      const unsigned short* __restrict__ Wt,
                                                      unsigned short* __restrict__ Cb, int M) {
    int w  = threadIdx.x >> 6;
    int l  = threadIdx.x & 63;
    int lr = l & 15, lg = l >> 4;

    bf16x8v bfr[8][4];
    #pragma unroll
    for (int nt = 0; nt < 8; ++nt)
        #pragma unroll
        for (int kk = 0; kk < 4; ++kk)
            bfr[nt][kk] = *reinterpret_cast<const bf16x8v*>(Wt + (nt * 16 + lr) * DD + kk * 32 + lg * 8);

    int tiles = (M + 63) >> 6;
    for (int t = blockIdx.x; t < tiles; t += gridDim.x) {
        int m0 = t * 64 + w * 16;
        int row = m0 + lr;
        int rowc = row < M ? row : (M - 1);

        bf16x8v af[4];
        if (AF32) {
            const float* Af = (const float*)Av;
            #pragma unroll
            for (int kk = 0; kk < 4; ++kk) {
                const float* p = Af + (size_t)rowc * DD + kk * 32 + lg * 8;
                float4 u0 = *reinterpret_cast<const float4*>(p);
                float4 u1 = *reinterpret_cast<const float4*>(p + 4);
                af[kk][0] = (__bf16)u0.x; af[kk][1] = (__bf16)u0.y;
                af[kk][2] = (__bf16)u0.z; af[kk][3] = (__bf16)u0.w;
                af[kk][4] = (__bf16)u1.x; af[kk][5] = (__bf16)u1.y;
                af[kk][6] = (__bf16)u1.z; af[kk][7] = (__bf16)u1.w;
            }
        } else {
            const unsigned short* Ab = (const unsigned short*)Av;
            #pragma unroll
            for (int kk = 0; kk < 4; ++kk)
                af[kk] = *reinterpret_cast<const bf16x8v*>(Ab + (size_t)rowc * DD + kk * 32 + lg * 8);
        }

        f32x4 acc[8] = {};
        #pragma unroll
        for (int kk = 0; kk < 4; ++kk)
            #pragma unroll
            for (int nt = 0; nt < 8; ++nt)
                acc[nt] = __builtin_amdgcn_mfma_f32_16x16x32_bf16(af[kk], bfr[nt][kk], acc[nt], 0, 0, 0);

        #pragma unroll
        for (int nt = 0; nt < 8; ++nt)
            #pragma unroll
            for (int r = 0; r < 4; ++r) {
                int rr = m0 + lg * 4 + r;
                if (rr < M) Cb[(size_t)rr * DD + nt * 16 + lr] = f2bf(acc[nt][r]);
            }
    }
}

// ---- padded-CSR gather: 4 rows/wave, all loads upfront, dinv[d] factored out ----
// acc = sum_e dinv[src]*h[src]; out = dinv[d]*acc + dinv[d]^2*h[d] + bias
template<int OUTF32, int RELU>
__global__ __launch_bounds__(256) void k_gather_pad(const int* __restrict__ fillc, const int* __restrict__ srcp,
                                                    const float* __restrict__ dinv, const unsigned* __restrict__ h32,
                                                    const float* __restrict__ bias, void* __restrict__ outp,
                                                    int N, const int* __restrict__ ovfcnt, const int2* __restrict__ ovf) {
    int l = threadIdx.x & 63;
    int g = blockIdx.x * 4 + (threadIdx.x >> 6);   // 4-row group id
    int m0 = g * 4;
    if (m0 >= N) return;
    float2 bb = reinterpret_cast<const float2*>(bias)[l];

    // degrees for the 4 rows (lanes 0..3)
    int fcidx = m0 + l; if (fcidx >= N) fcidx = N - 1;
    int fc = (l < 4) ? fillc[fcidx] : 0;

    int deg[4], c[4], sv[4], wvb[4];
    #pragma unroll
    for (int r = 0; r < 4; ++r) {
        deg[r] = __builtin_amdgcn_readlane(fc, r);
        int cc = deg[r] > CAP ? CAP : deg[r];
        c[r] = cc;
        int row = (m0 + r < N) ? (m0 + r) : (N - 1);
        sv[r] = (cc > 0) ? srcp[(size_t)row * CAP + (l < cc ? l : cc - 1)] : 0;
    }
    #pragma unroll
    for (int r = 0; r < 4; ++r)
        wvb[r] = __builtin_bit_cast(int, dinv[sv[r]]);   // per-lane gather of dinv[src]

    // upfront: 32 row loads + 4 self loads in flight before any consumption
    unsigned p[4][8]; float w[4][8];
    #pragma unroll
    for (int r = 0; r < 4; ++r) {
        int f = c[r] < 8 ? c[r] : 8;
        #pragma unroll
        for (int q = 0; q < 8; ++q) {
            int i = (q < f) ? q : (f > 0 ? f - 1 : 0);
            int s = __builtin_amdgcn_readlane(sv[r], i);
            p[r][q] = h32[(size_t)s * 64 + l];
            w[r][q] = (q < f) ? rl_f(wvb[r], i) : 0.f;
        }
    }
    unsigned ps[4];
    #pragma unroll
    for (int r = 0; r < 4; ++r) {
        int n = m0 + r; int nc = n < N ? n : N - 1;
        ps[r] = h32[(size_t)nc * 64 + l];
    }

    float ax[4] = {0.f, 0.f, 0.f, 0.f}, ay[4] = {0.f, 0.f, 0.f, 0.f};
    #pragma unroll
    for (int r = 0; r < 4; ++r)
        #pragma unroll
        for (int q = 0; q < 8; ++q) {
            ax[r] = fmaf(w[r][q], bflo2f(p[r][q]), ax[r]);
            ay[r] = fmaf(w[r][q], bfhi2f(p[r][q]), ay[r]);
        }

    // deg in (8,16]: remaining batch within the chunk registers
    #pragma unroll
    for (int r = 0; r < 4; ++r) {
        for (int i = 8; i < c[r]; i += 8) {
            #pragma unroll
            for (int q = 0; q < 8; ++q) {
                int ii = (i + q < c[r]) ? i + q : c[r] - 1;
                int s = __builtin_amdgcn_readlane(sv[r], ii);
                unsigned pp = h32[(size_t)s * 64 + l];
                float wq = (i + q < c[r]) ? rl_f(wvb[r], ii) : 0.f;
                ax[r] = fmaf(wq, bflo2f(pp), ax[r]);
                ay[r] = fmaf(wq, bfhi2f(pp), ay[r]);
            }
        }
    }

    // overflow (deg > CAP): exact fallback, ~25 rows / ~40 edges expected
    int anyovf = 0;
    #pragma unroll
    for (int r = 0; r < 4; ++r) anyovf |= (deg[r] > CAP) ? 1 : 0;
    if (anyovf) {
        int oc = *ovfcnt; if (oc > OVF_MAX) oc = OVF_MAX;
        for (int i = 0; i < oc; ++i) {
            int2 e = ovf[i];
            #pragma unroll
            for (int r = 0; r < 4; ++r) {
                if (deg[r] > CAP && e.y == m0 + r) {
                    float wq = dinv[e.x];
                    unsigned pp = h32[(size_t)e.x * 64 + l];
                    ax[r] = fmaf(wq, bflo2f(pp), ax[r]);
                    ay[r] = fmaf(wq, bfhi2f(pp), ay[r]);
                }
            }
        }
    }

    // epilogue: out = di*acc + di^2*self + bias
    #pragma unroll
    for (int r = 0; r < 4; ++r) {
        int n = m0 + r;
        if (n < N) {
            float di = rsqrtf(1.0f + (float)deg[r]);
            float di2 = di * di;
            float ox = fmaf(di2, bflo2f(ps[r]), di * ax[r]) + bb.x;
            float oy = fmaf(di2, bfhi2f(ps[r]), di * ay[r]) + bb.y;
            if (RELU) { ox = fmaxf(ox, 0.f); oy = fmaxf(oy, 0.f); }
            if (OUTF32) {
                reinterpret_cast<float2*>(outp)[(size_t)n * 64 + l] = make_float2(ox, oy);
            } else {
                unsigned po = (unsigned)f2bf(ox) | ((unsigned)f2bf(oy) << 16);
                reinterpret_cast<unsigned*>(outp)[(size_t)n * 64 + l] = po;
            }
        }
    }
}

extern "C" void kernel_launch(void* const* d_in, const int* in_sizes, int n_in,
                              void* d_out, int out_size, void* d_ws, size_t ws_size,
                              hipStream_t stream) {
    const float* x  = (const float*)d_in[0];
    const int*   ei = (const int*)d_in[1];
    const float* W1 = (const float*)d_in[2];
    const float* b1 = (const float*)d_in[3];
    const float* W2 = (const float*)d_in[4];
    const float* b2 = (const float*)d_in[5];
    // Wq/bq/Wk/bk (6..9) dead: softmax over seq_len=1 is identity.
    const float* Wv = (const float*)d_in[10];
    const float* bv = (const float*)d_in[11];
    const float* Wo = (const float*)d_in[12];
    const float* bo = (const float*)d_in[13];
    int N = in_sizes[0] / DD;
    int E = in_sizes[1] / 2;
    const int* src = ei;
    const int* dst = ei + E;
    float* out = (float*)d_out;

    unsigned* hA  = (unsigned*)d_ws;                  // N*64 u32 (bf16 GEMM out)
    unsigned* h1  = hA + (size_t)N * 64;              // N*64 u32 (bf16 h1)
    float* dinv   = (float*)(h1 + (size_t)N * 64);    // N
    float* Wf     = dinv + N;                         // 128*128 f32
    float* bfo    = Wf + DD * DD;                     // 128
    float* bf2    = bfo + DD;                         // 128
    unsigned short* Wt1  = (unsigned short*)(bf2 + DD);   // 128*128 bf16
    unsigned short* W2ft = Wt1 + DD * DD;                 // 128*128 bf16
    int* fillc  = (int*)(W2ft + DD * DD);             // N (+1 for ovfcnt)
    int* ovfcnt = fillc + N;                          // 1
    int2* ovf   = (int2*)(((uintptr_t)(ovfcnt + 1) + 63) & ~(uintptr_t)63);   // OVF_MAX
    int* srcp   = (int*)(((uintptr_t)(ovf + OVF_MAX) + 63) & ~(uintptr_t)63); // N*CAP, 64B-aligned

    int nb = (N + 255) / 256;
    int nchunks = (E + ECHUNK - 1) / ECHUNK;
    int FB = nchunks * 8;   // 8 XCD bins per edge chunk

    // D1: zero fillc + ovfcnt
    k_zero<<<512, 256, 0, stream>>>(fillc, N);
    // D2: XCD-local padded fill + MHA weight fold
    k_fill_fuse1<<<FB + 129, 256, 0, stream>>>(src, dst, fillc, srcp, ovfcnt, ovf, E, N, FB,
                                               Wv, Wo, bv, bo, Wf, bfo);
    // D3: dinv + weight transposes (needs fillc, Wf from D2)
    k_dinv_wprep<<<nb + 129, 256, 0, stream>>>(fillc, dinv, N, nb,
                                               W2, Wf, b2, bfo, W2ft, bf2, W1, Wt1);
    // D4: layer-1 GEMM: hA = bf16(x @ W1)
    k_gemm_mfma<1><<<512, 256, 0, stream>>>(x, Wt1, (unsigned short*)hA, N);
    int nwaves = (N + 3) / 4;
    int gb = (nwaves + 3) / 4;   // 4 waves/block, 4 rows/wave
    // D5: gather layer 1 -> h1 (bf16, relu, +b1)
    k_gather_pad<0, 1><<<gb, 256, 0, stream>>>(fillc, srcp, dinv, hA, b1, h1, N, ovfcnt, ovf);
    // D6: layer-2 GEMM (W2·Wv·Wo folded): hA = bf16(h1 @ W2f)
    k_gemm_mfma<0><<<512, 256, 0, stream>>>(h1, W2ft, (unsigned short*)hA, N);
    // D7: gather layer 2 -> out (f32, +bf2)
    k_gather_pad<1, 0><<<gb, 256, 0, stream>>>(fillc, srcp, dinv, hA, bf2, out, N, ovfcnt, ovf);
}

// Round 20
// 161.782 us; speedup vs baseline: 1.0588x; 1.0249x over previous
//
#include <hip/hip_runtime.h>
#include <hip/hip_bf16.h>

#define DD 128
#define CAP 16          // one 64B cache line per row
#define OVF_MAX 8192
#define ECHUNK 2048     // edges per fill block

typedef __bf16 bf16x8v __attribute__((ext_vector_type(8)));
typedef float  f32x4   __attribute__((ext_vector_type(4)));

__device__ inline unsigned short f2bf(float f) {
    unsigned u = __builtin_bit_cast(unsigned, f);
    unsigned r = (u + 0x7fffu + ((u >> 16) & 1u)) >> 16;
    return (unsigned short)r;
}
__device__ inline float bflo2f(unsigned p) { return __builtin_bit_cast(float, p << 16); }
__device__ inline float bfhi2f(unsigned p) { return __builtin_bit_cast(float, p & 0xffff0000u); }
__device__ inline float rl_f(int v, int i) {
    return __builtin_bit_cast(float, __builtin_amdgcn_readlane(v, i));
}

// ---- zero fillc[N] + ovfcnt ----
__global__ __launch_bounds__(256) void k_zero(int* __restrict__ a, int N) {
    int i = blockIdx.x * 256 + threadIdx.x;
    int stride = gridDim.x * 256;
    for (; i <= N; i += stride) a[i] = 0;   // N fillc + 1 ovfcnt (a[N])
}

// ---- XCD-local padded fill + fuse1 (Wf = Wv@Wo, bfo = bv@Wo+bo) ----
__global__ __launch_bounds__(256) void k_fill_fuse1(const int* __restrict__ src, const int* __restrict__ dst,
                                                    int* __restrict__ fillc, int* __restrict__ srcp,
                                                    int* __restrict__ ovfcnt, int2* __restrict__ ovf,
                                                    int E, int N, int FB,
                                                    const float* __restrict__ Wv, const float* __restrict__ Wo,
                                                    const float* __restrict__ bv, const float* __restrict__ bo,
                                                    float* __restrict__ Wf, float* __restrict__ bfo) {
    if ((int)blockIdx.x < FB) {
        int bin   = blockIdx.x & 7;
        int chunk = blockIdx.x >> 3;
        int binsz = (N + 7) / 8;
        int lo = bin * binsz;
        int hi = lo + binsz; if (hi > N) hi = N;
        int base = chunk * ECHUNK + threadIdx.x;
        #pragma unroll
        for (int i = 0; i < ECHUNK / 256; ++i) {
            int e = base + i * 256;
            if (e < E) {
                int d = dst[e];
                if (d >= lo && d < hi) {
                    int s = src[e];
                    if ((unsigned)s < (unsigned)N) {
                        int pos = atomicAdd(&fillc[d], 1);
                        if (pos < CAP) srcp[(size_t)d * CAP + pos] = s;
                        else {
                            int op = atomicAdd(ovfcnt, 1);
                            if (op < OVF_MAX) ovf[op] = make_int2(s, d);
                        }
                    }
                }
            }
        }
    } else {
        int gid = (blockIdx.x - FB) * 256 + threadIdx.x;
        if (gid >= (DD + 1) * DD) return;
        int i = gid >> 7, j = gid & (DD - 1);
        if (i < DD) {
            float acc = 0.f;
            for (int k = 0; k < DD; ++k) acc = fmaf(Wv[i * DD + k], Wo[k * DD + j], acc);
            Wf[i * DD + j] = acc;
        } else {
            float acc = bo[j];
            for (int k = 0; k < DD; ++k) acc = fmaf(bv[k], Wo[k * DD + j], acc);
            bfo[j] = acc;
        }
    }
}

// ---- dinv from fillc + weight prep (W2f^T bf16, bf2, Wt1) ----
__global__ __launch_bounds__(256) void k_dinv_wprep(const int* __restrict__ fillc, float* __restrict__ dinv,
                                                    int N, int nb,
                                                    const float* __restrict__ W2, const float* __restrict__ Wf,
                                                    const float* __restrict__ b2, const float* __restrict__ bfo,
                                                    unsigned short* __restrict__ W2ft, float* __restrict__ bf2,
                                                    const float* __restrict__ W1, unsigned short* __restrict__ Wt1) {
    if ((int)blockIdx.x < nb) {
        int n = blockIdx.x * 256 + threadIdx.x;
        if (n < N) dinv[n] = rsqrtf(1.0f + (float)fillc[n]);
    } else {
        int blk = blockIdx.x - nb;
        if (blk < 65) {
            int gid = blk * 256 + threadIdx.x;
            if (gid >= (DD + 1) * DD) return;
            int i = gid >> 7, j = gid & (DD - 1);
            if (i < DD) {
                float acc = 0.f;
                for (int k = 0; k < DD; ++k) acc = fmaf(W2[i * DD + k], Wf[k * DD + j], acc);
                W2ft[j * DD + i] = f2bf(acc);       // transposed bf16
            } else {
                float acc = bfo[j];
                for (int k = 0; k < DD; ++k) acc = fmaf(b2[k], Wf[k * DD + j], acc);
                bf2[j] = acc;
            }
        } else {
            int gid = (blk - 65) * 256 + threadIdx.x;   // 16384
            int k = gid >> 7, n = gid & 127;
            Wt1[n * DD + k] = f2bf(W1[k * DD + n]);
        }
    }
}

// ---- MFMA GEMM: Cb[M x 128] bf16 = A[M x 128] @ Wt^T (layer 1, f32 A) ----
__global__ __launch_bounds__(256, 2) void k_gemm_mfma(const float* __restrict__ Af,
                                                      const unsigned short* __restrict__ Wt,
                                                      unsigned short* __restrict__ Cb, int M) {
    int w  = threadIdx.x >> 6;
    int l  = threadIdx.x & 63;
    int lr = l & 15, lg = l >> 4;

    bf16x8v bfr[8][4];
    #pragma unroll
    for (int nt = 0; nt < 8; ++nt)
        #pragma unroll
        for (int kk = 0; kk < 4; ++kk)
            bfr[nt][kk] = *reinterpret_cast<const bf16x8v*>(Wt + (nt * 16 + lr) * DD + kk * 32 + lg * 8);

    int tiles = (M + 63) >> 6;
    for (int t = blockIdx.x; t < tiles; t += gridDim.x) {
        int m0 = t * 64 + w * 16;
        int row = m0 + lr;
        int rowc = row < M ? row : (M - 1);

        bf16x8v af[4];
        #pragma unroll
        for (int kk = 0; kk < 4; ++kk) {
            const float* p = Af + (size_t)rowc * DD + kk * 32 + lg * 8;
            float4 u0 = *reinterpret_cast<const float4*>(p);
            float4 u1 = *reinterpret_cast<const float4*>(p + 4);
            af[kk][0] = (__bf16)u0.x; af[kk][1] = (__bf16)u0.y;
            af[kk][2] = (__bf16)u0.z; af[kk][3] = (__bf16)u0.w;
            af[kk][4] = (__bf16)u1.x; af[kk][5] = (__bf16)u1.y;
            af[kk][6] = (__bf16)u1.z; af[kk][7] = (__bf16)u1.w;
        }

        f32x4 acc[8] = {};
        #pragma unroll
        for (int kk = 0; kk < 4; ++kk)
            #pragma unroll
            for (int nt = 0; nt < 8; ++nt)
                acc[nt] = __builtin_amdgcn_mfma_f32_16x16x32_bf16(af[kk], bfr[nt][kk], acc[nt], 0, 0, 0);

        #pragma unroll
        for (int nt = 0; nt < 8; ++nt)
            #pragma unroll
            for (int r = 0; r < 4; ++r) {
                int rr = m0 + lg * 4 + r;
                if (rr < M) Cb[(size_t)rr * DD + nt * 16 + lr] = f2bf(acc[nt][r]);
            }
    }
}

// ---- FUSED gather1 + gemm2: per 16-row block, 4 waves x 4 rows gather
//      relu(G(hA)+b1) into LDS, barrier, MFMA x W2ft -> hA2 bf16 ----
__global__ __launch_bounds__(256) void k_gg(const int* __restrict__ fillc, const int* __restrict__ srcp,
                                            const float* __restrict__ dinv, const unsigned* __restrict__ h32,
                                            const float* __restrict__ b1, const unsigned short* __restrict__ W2ft,
                                            unsigned short* __restrict__ hA2, int N,
                                            const int* __restrict__ ovfcnt, const int2* __restrict__ ovf) {
    __shared__ unsigned short Wl[128][136];   // +8 shorts pad -> 17x16B rows, balanced quads
    __shared__ unsigned short agg[16][136];
    int t = threadIdx.x;
    // stage W2ft (8192 u32), coalesced, L2-hot
    {
        const unsigned* Wsrc = (const unsigned*)W2ft;
        #pragma unroll
        for (int i = 0; i < 32; ++i) {
            int idx = t + i * 256;
            int row = idx >> 6, col = idx & 63;
            *reinterpret_cast<unsigned*>(&Wl[row][col * 2]) = Wsrc[idx];
        }
    }
    int l = t & 63;
    int w = t >> 6;
    int m0 = blockIdx.x * 16 + w * 4;   // this wave's 4 rows

    // ---- gather phase (proven 4-row upfront structure) ----
    float2 bb = reinterpret_cast<const float2*>(b1)[l];
    int fcidx = m0 + l; if (fcidx >= N) fcidx = N - 1;
    int fc = (l < 4) ? fillc[fcidx] : 0;

    int deg[4], c[4], sv[4], wvb[4];
    #pragma unroll
    for (int r = 0; r < 4; ++r) {
        deg[r] = __builtin_amdgcn_readlane(fc, r);
        int cc = deg[r] > CAP ? CAP : deg[r];
        c[r] = cc;
        int row = (m0 + r < N) ? (m0 + r) : (N - 1);
        sv[r] = (cc > 0) ? srcp[(size_t)row * CAP + (l < cc ? l : cc - 1)] : 0;
    }
    #pragma unroll
    for (int r = 0; r < 4; ++r)
        wvb[r] = __builtin_bit_cast(int, dinv[sv[r]]);

    unsigned p[4][8]; float wgt[4][8];
    #pragma unroll
    for (int r = 0; r < 4; ++r) {
        int f = c[r] < 8 ? c[r] : 8;
        #pragma unroll
        for (int q = 0; q < 8; ++q) {
            int i = (q < f) ? q : (f > 0 ? f - 1 : 0);
            int s = __builtin_amdgcn_readlane(sv[r], i);
            p[r][q] = h32[(size_t)s * 64 + l];
            wgt[r][q] = (q < f) ? rl_f(wvb[r], i) : 0.f;
        }
    }
    unsigned ps[4];
    #pragma unroll
    for (int r = 0; r < 4; ++r) {
        int n = m0 + r; int nc = n < N ? n : N - 1;
        ps[r] = h32[(size_t)nc * 64 + l];
    }

    float ax[4] = {0.f, 0.f, 0.f, 0.f}, ay[4] = {0.f, 0.f, 0.f, 0.f};
    #pragma unroll
    for (int r = 0; r < 4; ++r)
        #pragma unroll
        for (int q = 0; q < 8; ++q) {
            ax[r] = fmaf(wgt[r][q], bflo2f(p[r][q]), ax[r]);
            ay[r] = fmaf(wgt[r][q], bfhi2f(p[r][q]), ay[r]);
        }
    #pragma unroll
    for (int r = 0; r < 4; ++r) {
        for (int i = 8; i < c[r]; i += 8) {
            #pragma unroll
            for (int q = 0; q < 8; ++q) {
                int ii = (i + q < c[r]) ? i + q : c[r] - 1;
                int s = __builtin_amdgcn_readlane(sv[r], ii);
                unsigned pp = h32[(size_t)s * 64 + l];
                float wq = (i + q < c[r]) ? rl_f(wvb[r], ii) : 0.f;
                ax[r] = fmaf(wq, bflo2f(pp), ax[r]);
                ay[r] = fmaf(wq, bfhi2f(pp), ay[r]);
            }
        }
    }
    int anyovf = 0;
    #pragma unroll
    for (int r = 0; r < 4; ++r) anyovf |= (deg[r] > CAP) ? 1 : 0;
    if (anyovf) {
        int oc = *ovfcnt; if (oc > OVF_MAX) oc = OVF_MAX;
        for (int i = 0; i < oc; ++i) {
            int2 e = ovf[i];
            #pragma unroll
            for (int r = 0; r < 4; ++r) {
                if (deg[r] > CAP && e.y == m0 + r) {
                    float wq = dinv[e.x];
                    unsigned pp = h32[(size_t)e.x * 64 + l];
                    ax[r] = fmaf(wq, bflo2f(pp), ax[r]);
                    ay[r] = fmaf(wq, bfhi2f(pp), ay[r]);
                }
            }
        }
    }
    #pragma unroll
    for (int r = 0; r < 4; ++r) {
        int n = m0 + r;
        float di = rsqrtf(1.0f + (float)deg[r]);
        float di2 = di * di;
        float ox = fmaf(di2, bflo2f(ps[r]), di * ax[r]) + bb.x;
        float oy = fmaf(di2, bfhi2f(ps[r]), di * ay[r]) + bb.y;
        ox = fmaxf(ox, 0.f); oy = fmaxf(oy, 0.f);           // relu (layer 1)
        unsigned po = (n < N) ? ((unsigned)f2bf(ox) | ((unsigned)f2bf(oy) << 16)) : 0u;
        *reinterpret_cast<unsigned*>(&agg[w * 4 + r][l * 2]) = po;
    }
    __syncthreads();

    // ---- MFMA phase: C[16x128] = agg[16x128] @ W2ft^T; wave w -> n-tiles 2w,2w+1 ----
    int lr = l & 15, lg = l >> 4;
    f32x4 acc[2] = {};
    #pragma unroll
    for (int kk = 0; kk < 4; ++kk) {
        bf16x8v af = *reinterpret_cast<const bf16x8v*>(&agg[lr][kk * 32 + lg * 8]);
        #pragma unroll
        for (int j = 0; j < 2; ++j) {
            int nt = w * 2 + j;
            bf16x8v bfrag = *reinterpret_cast<const bf16x8v*>(&Wl[nt * 16 + lr][kk * 32 + lg * 8]);
            acc[j] = __builtin_amdgcn_mfma_f32_16x16x32_bf16(af, bfrag, acc[j], 0, 0, 0);
        }
    }
    int mb = blockIdx.x * 16;
    #pragma unroll
    for (int j = 0; j < 2; ++j) {
        int nt = w * 2 + j;
        #pragma unroll
        for (int r4 = 0; r4 < 4; ++r4) {
            int rr = mb + lg * 4 + r4;
            if (rr < N) hA2[(size_t)rr * DD + nt * 16 + lr] = f2bf(acc[j][r4]);
        }
    }
}

// ---- padded-CSR gather (layer 2 out): 4 rows/wave, f32 out + bf2, no relu ----
__global__ __launch_bounds__(256) void k_gather_pad(const int* __restrict__ fillc, const int* __restrict__ srcp,
                                                    const float* __restrict__ dinv, const unsigned* __restrict__ h32,
                                                    const float* __restrict__ bias, float* __restrict__ outp,
                                                    int N, const int* __restrict__ ovfcnt, const int2* __restrict__ ovf) {
    int l = threadIdx.x & 63;
    int g = blockIdx.x * 4 + (threadIdx.x >> 6);
    int m0 = g * 4;
    if (m0 >= N) return;
    float2 bb = reinterpret_cast<const float2*>(bias)[l];

    int fcidx = m0 + l; if (fcidx >= N) fcidx = N - 1;
    int fc = (l < 4) ? fillc[fcidx] : 0;

    int deg[4], c[4], sv[4], wvb[4];
    #pragma unroll
    for (int r = 0; r < 4; ++r) {
        deg[r] = __builtin_amdgcn_readlane(fc, r);
        int cc = deg[r] > CAP ? CAP : deg[r];
        c[r] = cc;
        int row = (m0 + r < N) ? (m0 + r) : (N - 1);
        sv[r] = (cc > 0) ? srcp[(size_t)row * CAP + (l < cc ? l : cc - 1)] : 0;
    }
    #pragma unroll
    for (int r = 0; r < 4; ++r)
        wvb[r] = __builtin_bit_cast(int, dinv[sv[r]]);

    unsigned p[4][8]; float w[4][8];
    #pragma unroll
    for (int r = 0; r < 4; ++r) {
        int f = c[r] < 8 ? c[r] : 8;
        #pragma unroll
        for (int q = 0; q < 8; ++q) {
            int i = (q < f) ? q : (f > 0 ? f - 1 : 0);
            int s = __builtin_amdgcn_readlane(sv[r], i);
            p[r][q] = h32[(size_t)s * 64 + l];
            w[r][q] = (q < f) ? rl_f(wvb[r], i) : 0.f;
        }
    }
    unsigned ps[4];
    #pragma unroll
    for (int r = 0; r < 4; ++r) {
        int n = m0 + r; int nc = n < N ? n : N - 1;
        ps[r] = h32[(size_t)nc * 64 + l];
    }

    float ax[4] = {0.f, 0.f, 0.f, 0.f}, ay[4] = {0.f, 0.f, 0.f, 0.f};
    #pragma unroll
    for (int r = 0; r < 4; ++r)
        #pragma unroll
        for (int q = 0; q < 8; ++q) {
            ax[r] = fmaf(w[r][q], bflo2f(p[r][q]), ax[r]);
            ay[r] = fmaf(w[r][q], bfhi2f(p[r][q]), ay[r]);
        }
    #pragma unroll
    for (int r = 0; r < 4; ++r) {
        for (int i = 8; i < c[r]; i += 8) {
            #pragma unroll
            for (int q = 0; q < 8; ++q) {
                int ii = (i + q < c[r]) ? i + q : c[r] - 1;
                int s = __builtin_amdgcn_readlane(sv[r], ii);
                unsigned pp = h32[(size_t)s * 64 + l];
                float wq = (i + q < c[r]) ? rl_f(wvb[r], ii) : 0.f;
                ax[r] = fmaf(wq, bflo2f(pp), ax[r]);
                ay[r] = fmaf(wq, bfhi2f(pp), ay[r]);
            }
        }
    }
    int anyovf = 0;
    #pragma unroll
    for (int r = 0; r < 4; ++r) anyovf |= (deg[r] > CAP) ? 1 : 0;
    if (anyovf) {
        int oc = *ovfcnt; if (oc > OVF_MAX) oc = OVF_MAX;
        for (int i = 0; i < oc; ++i) {
            int2 e = ovf[i];
            #pragma unroll
            for (int r = 0; r < 4; ++r) {
                if (deg[r] > CAP && e.y == m0 + r) {
                    float wq = dinv[e.x];
                    unsigned pp = h32[(size_t)e.x * 64 + l];
                    ax[r] = fmaf(wq, bflo2f(pp), ax[r]);
                    ay[r] = fmaf(wq, bfhi2f(pp), ay[r]);
                }
            }
        }
    }
    #pragma unroll
    for (int r = 0; r < 4; ++r) {
        int n = m0 + r;
        if (n < N) {
            float di = rsqrtf(1.0f + (float)deg[r]);
            float di2 = di * di;
            float ox = fmaf(di2, bflo2f(ps[r]), di * ax[r]) + bb.x;
            float oy = fmaf(di2, bfhi2f(ps[r]), di * ay[r]) + bb.y;
            reinterpret_cast<float2*>(outp)[(size_t)n * 64 + l] = make_float2(ox, oy);
        }
    }
}

extern "C" void kernel_launch(void* const* d_in, const int* in_sizes, int n_in,
                              void* d_out, int out_size, void* d_ws, size_t ws_size,
                              hipStream_t stream) {
    const float* x  = (const float*)d_in[0];
    const int*   ei = (const int*)d_in[1];
    const float* W1 = (const float*)d_in[2];
    const float* b1 = (const float*)d_in[3];
    const float* W2 = (const float*)d_in[4];
    const float* b2 = (const float*)d_in[5];
    // Wq/bq/Wk/bk (6..9) dead: softmax over seq_len=1 is identity.
    const float* Wv = (const float*)d_in[10];
    const float* bv = (const float*)d_in[11];
    const float* Wo = (const float*)d_in[12];
    const float* bo = (const float*)d_in[13];
    int N = in_sizes[0] / DD;
    int E = in_sizes[1] / 2;
    const int* src = ei;
    const int* dst = ei + E;
    float* out = (float*)d_out;

    unsigned* hA  = (unsigned*)d_ws;                  // N*64 u32 (gemm1 out, bf16)
    unsigned* hA2 = hA + (size_t)N * 64;              // N*64 u32 (fused out, bf16)
    float* dinv   = (float*)(hA2 + (size_t)N * 64);   // N
    float* Wf     = dinv + N;                         // 128*128 f32
    float* bfo    = Wf + DD * DD;                     // 128
    float* bf2    = bfo + DD;                         // 128
    unsigned short* Wt1  = (unsigned short*)(bf2 + DD);   // 128*128 bf16
    unsigned short* W2ft = Wt1 + DD * DD;                 // 128*128 bf16
    int* fillc  = (int*)(W2ft + DD * DD);             // N (+1 for ovfcnt)
    int* ovfcnt = fillc + N;                          // 1
    int2* ovf   = (int2*)(((uintptr_t)(ovfcnt + 1) + 63) & ~(uintptr_t)63);   // OVF_MAX
    int* srcp   = (int*)(((uintptr_t)(ovf + OVF_MAX) + 63) & ~(uintptr_t)63); // N*CAP, 64B-aligned

    int nb = (N + 255) / 256;
    int nchunks = (E + ECHUNK - 1) / ECHUNK;
    int FB = nchunks * 8;   // 8 XCD bins per edge chunk

    // D1: zero fillc + ovfcnt
    k_zero<<<512, 256, 0, stream>>>(fillc, N);
    // D2: XCD-local padded fill + MHA weight fold
    k_fill_fuse1<<<FB + 129, 256, 0, stream>>>(src, dst, fillc, srcp, ovfcnt, ovf, E, N, FB,
                                               Wv, Wo, bv, bo, Wf, bfo);
    // D3: dinv + weight transposes
    k_dinv_wprep<<<nb + 129, 256, 0, stream>>>(fillc, dinv, N, nb,
                                               W2, Wf, b2, bfo, W2ft, bf2, W1, Wt1);
    // D4: layer-1 GEMM: hA = bf16(x @ W1)
    k_gemm_mfma<<<512, 256, 0, stream>>>(x, Wt1, (unsigned short*)hA, N);
    // D5: FUSED gather1+gemm2: hA2 = bf16( relu(G(hA)+b1) @ W2f )
    int ggb = (N + 15) / 16;
    k_gg<<<ggb, 256, 0, stream>>>(fillc, srcp, dinv, hA, b1, W2ft, (unsigned short*)hA2, N, ovfcnt, ovf);
    // D6: gather layer 2 -> out (f32, +bf2)
    int gb = ((N + 3) / 4 + 3) / 4;
    k_gather_pad<<<gb, 256, 0, stream>>>(fillc, srcp, dinv, hA2, bf2, out, N, ovfcnt, ovf);
}

// Round 21
// 157.051 us; speedup vs baseline: 1.0907x; 1.0301x over previous
//
#include <hip/hip_runtime.h>
#include <hip/hip_bf16.h>

#define DD 128
#define CAP 16          // one 64B cache line per row
#define OVF_MAX 8192
#define ECHUNK 2048     // edges per fill block

typedef __bf16 bf16x8v __attribute__((ext_vector_type(8)));
typedef float  f32x4   __attribute__((ext_vector_type(4)));

__device__ inline unsigned short f2bf(float f) {
    unsigned u = __builtin_bit_cast(unsigned, f);
    unsigned r = (u + 0x7fffu + ((u >> 16) & 1u)) >> 16;
    return (unsigned short)r;
}
__device__ inline float bflo2f(unsigned p) { return __builtin_bit_cast(float, p << 16); }
__device__ inline float bfhi2f(unsigned p) { return __builtin_bit_cast(float, p & 0xffff0000u); }
__device__ inline float rl_f(int v, int i) {
    return __builtin_bit_cast(float, __builtin_amdgcn_readlane(v, i));
}

// ---- D1: zero fillc/ovfcnt  ||  Wf = Wv@Wo, bfo = bv@Wo+bo  ||  Wt1 = W1^T bf16 ----
__global__ __launch_bounds__(256) void k_prep1(int* __restrict__ fillc, int N, int ZB,
                                               const float* __restrict__ Wv, const float* __restrict__ Wo,
                                               const float* __restrict__ bv, const float* __restrict__ bo,
                                               float* __restrict__ Wf, float* __restrict__ bfo,
                                               const float* __restrict__ W1, unsigned short* __restrict__ Wt1) {
    int blk = blockIdx.x;
    if (blk < ZB) {
        int i = blk * 256 + threadIdx.x;
        int stride = ZB * 256;
        for (; i <= N; i += stride) fillc[i] = 0;   // N fillc + ovfcnt at [N]
    } else if (blk < ZB + 65) {
        int gid = (blk - ZB) * 256 + threadIdx.x;
        if (gid >= (DD + 1) * DD) return;
        int i = gid >> 7, j = gid & (DD - 1);
        if (i < DD) {
            float acc = 0.f;
            for (int k = 0; k < DD; ++k) acc = fmaf(Wv[i * DD + k], Wo[k * DD + j], acc);
            Wf[i * DD + j] = acc;
        } else {
            float acc = bo[j];
            for (int k = 0; k < DD; ++k) acc = fmaf(bv[k], Wo[k * DD + j], acc);
            bfo[j] = acc;
        }
    } else {
        int gid = (blk - ZB - 65) * 256 + threadIdx.x;   // 16384
        int k = gid >> 7, n = gid & 127;
        Wt1[n * DD + k] = f2bf(W1[k * DD + n]);
    }
}

// ---- D2: XCD-local padded fill  ||  W2ft = (W2@Wf)^T bf16, bf2 = b2@Wf + bfo ----
__global__ __launch_bounds__(256) void k_fill_wprep(const int* __restrict__ src, const int* __restrict__ dst,
                                                    int* __restrict__ fillc, int* __restrict__ srcp,
                                                    int* __restrict__ ovfcnt, int2* __restrict__ ovf,
                                                    int E, int N, int FB,
                                                    const float* __restrict__ W2, const float* __restrict__ Wf,
                                                    const float* __restrict__ b2, const float* __restrict__ bfo,
                                                    unsigned short* __restrict__ W2ft, float* __restrict__ bf2) {
    if ((int)blockIdx.x < FB) {
        int bin   = blockIdx.x & 7;
        int chunk = blockIdx.x >> 3;
        int binsz = (N + 7) / 8;
        int lo = bin * binsz;
        int hi = lo + binsz; if (hi > N) hi = N;
        int base = chunk * ECHUNK + threadIdx.x;
        #pragma unroll
        for (int i = 0; i < ECHUNK / 256; ++i) {
            int e = base + i * 256;
            if (e < E) {
                int d = dst[e];
                if (d >= lo && d < hi) {
                    int s = src[e];
                    if ((unsigned)s < (unsigned)N) {
                        int pos = atomicAdd(&fillc[d], 1);
                        if (pos < CAP) srcp[(size_t)d * CAP + pos] = s;
                        else {
                            int op = atomicAdd(ovfcnt, 1);
                            if (op < OVF_MAX) ovf[op] = make_int2(s, d);
                        }
                    }
                }
            }
        }
    } else {
        int gid = (blockIdx.x - FB) * 256 + threadIdx.x;
        if (gid >= (DD + 1) * DD) return;
        int i = gid >> 7, j = gid & (DD - 1);
        if (i < DD) {
            float acc = 0.f;
            for (int k = 0; k < DD; ++k) acc = fmaf(W2[i * DD + k], Wf[k * DD + j], acc);
            W2ft[j * DD + i] = f2bf(acc);       // transposed bf16
        } else {
            float acc = bfo[j];
            for (int k = 0; k < DD; ++k) acc = fmaf(b2[k], Wf[k * DD + j], acc);
            bf2[j] = acc;
        }
    }
}

// ---- D3: MFMA GEMM: hA[M x 128] bf16 = bf16(x f32) @ Wt1^T ----
__global__ __launch_bounds__(256, 2) void k_gemm_mfma(const float* __restrict__ Af,
                                                      const unsigned short* __restrict__ Wt,
                                                      unsigned short* __restrict__ Cb, int M) {
    int w  = threadIdx.x >> 6;
    int l  = threadIdx.x & 63;
    int lr = l & 15, lg = l >> 4;

    bf16x8v bfr[8][4];
    #pragma unroll
    for (int nt = 0; nt < 8; ++nt)
        #pragma unroll
        for (int kk = 0; kk < 4; ++kk)
            bfr[nt][kk] = *reinterpret_cast<const bf16x8v*>(Wt + (nt * 16 + lr) * DD + kk * 32 + lg * 8);

    int tiles = (M + 63) >> 6;
    for (int t = blockIdx.x; t < tiles; t += gridDim.x) {
        int m0 = t * 64 + w * 16;
        int row = m0 + lr;
        int rowc = row < M ? row : (M - 1);

        bf16x8v af[4];
        #pragma unroll
        for (int kk = 0; kk < 4; ++kk) {
            const float* p = Af + (size_t)rowc * DD + kk * 32 + lg * 8;
            float4 u0 = *reinterpret_cast<const float4*>(p);
            float4 u1 = *reinterpret_cast<const float4*>(p + 4);
            af[kk][0] = (__bf16)u0.x; af[kk][1] = (__bf16)u0.y;
            af[kk][2] = (__bf16)u0.z; af[kk][3] = (__bf16)u0.w;
            af[kk][4] = (__bf16)u1.x; af[kk][5] = (__bf16)u1.y;
            af[kk][6] = (__bf16)u1.z; af[kk][7] = (__bf16)u1.w;
        }

        f32x4 acc[8] = {};
        #pragma unroll
        for (int kk = 0; kk < 4; ++kk)
            #pragma unroll
            for (int nt = 0; nt < 8; ++nt)
                acc[nt] = __builtin_amdgcn_mfma_f32_16x16x32_bf16(af[kk], bfr[nt][kk], acc[nt], 0, 0, 0);

        #pragma unroll
        for (int nt = 0; nt < 8; ++nt)
            #pragma unroll
            for (int r = 0; r < 4; ++r) {
                int rr = m0 + lg * 4 + r;
                if (rr < M) Cb[(size_t)rr * DD + nt * 16 + lr] = f2bf(acc[nt][r]);
            }
    }
}

// ---- D4: FUSED gather1 + gemm2 (dinv computed from fillc on the fly) ----
__global__ __launch_bounds__(256) void k_gg(const int* __restrict__ fillc, const int* __restrict__ srcp,
                                            const unsigned* __restrict__ h32,
                                            const float* __restrict__ b1, const unsigned short* __restrict__ W2ft,
                                            unsigned short* __restrict__ hA2, int N,
                                            const int* __restrict__ ovfcnt, const int2* __restrict__ ovf) {
    __shared__ unsigned short Wl[128][136];   // +8 shorts pad -> balanced bank quads
    __shared__ unsigned short agg[16][136];
    int t = threadIdx.x;
    {
        const unsigned* Wsrc = (const unsigned*)W2ft;
        #pragma unroll
        for (int i = 0; i < 32; ++i) {
            int idx = t + i * 256;
            int row = idx >> 6, col = idx & 63;
            *reinterpret_cast<unsigned*>(&Wl[row][col * 2]) = Wsrc[idx];
        }
    }
    int l = t & 63;
    int w = t >> 6;
    int m0 = blockIdx.x * 16 + w * 4;

    float2 bb = reinterpret_cast<const float2*>(b1)[l];
    int fcidx = m0 + l; if (fcidx >= N) fcidx = N - 1;
    int fc = (l < 4) ? fillc[fcidx] : 0;

    int deg[4], c[4], sv[4], wvb[4];
    #pragma unroll
    for (int r = 0; r < 4; ++r) {
        deg[r] = __builtin_amdgcn_readlane(fc, r);
        int cc = deg[r] > CAP ? CAP : deg[r];
        c[r] = cc;
        int row = (m0 + r < N) ? (m0 + r) : (N - 1);
        sv[r] = (cc > 0) ? srcp[(size_t)row * CAP + (l < cc ? l : cc - 1)] : 0;
    }
    #pragma unroll
    for (int r = 0; r < 4; ++r)
        wvb[r] = __builtin_bit_cast(int, rsqrtf(1.0f + (float)fillc[sv[r]]));

    unsigned p[4][8]; float wgt[4][8];
    #pragma unroll
    for (int r = 0; r < 4; ++r) {
        int f = c[r] < 8 ? c[r] : 8;
        #pragma unroll
        for (int q = 0; q < 8; ++q) {
            int i = (q < f) ? q : (f > 0 ? f - 1 : 0);
            int s = __builtin_amdgcn_readlane(sv[r], i);
            p[r][q] = h32[(size_t)s * 64 + l];
            wgt[r][q] = (q < f) ? rl_f(wvb[r], i) : 0.f;
        }
    }
    unsigned ps[4];
    #pragma unroll
    for (int r = 0; r < 4; ++r) {
        int n = m0 + r; int nc = n < N ? n : N - 1;
        ps[r] = h32[(size_t)nc * 64 + l];
    }

    float ax[4] = {0.f, 0.f, 0.f, 0.f}, ay[4] = {0.f, 0.f, 0.f, 0.f};
    #pragma unroll
    for (int r = 0; r < 4; ++r)
        #pragma unroll
        for (int q = 0; q < 8; ++q) {
            ax[r] = fmaf(wgt[r][q], bflo2f(p[r][q]), ax[r]);
            ay[r] = fmaf(wgt[r][q], bfhi2f(p[r][q]), ay[r]);
        }
    #pragma unroll
    for (int r = 0; r < 4; ++r) {
        for (int i = 8; i < c[r]; i += 8) {
            #pragma unroll
            for (int q = 0; q < 8; ++q) {
                int ii = (i + q < c[r]) ? i + q : c[r] - 1;
                int s = __builtin_amdgcn_readlane(sv[r], ii);
                unsigned pp = h32[(size_t)s * 64 + l];
                float wq = (i + q < c[r]) ? rl_f(wvb[r], ii) : 0.f;
                ax[r] = fmaf(wq, bflo2f(pp), ax[r]);
                ay[r] = fmaf(wq, bfhi2f(pp), ay[r]);
            }
        }
    }
    int anyovf = 0;
    #pragma unroll
    for (int r = 0; r < 4; ++r) anyovf |= (deg[r] > CAP) ? 1 : 0;
    if (anyovf) {
        int oc = *ovfcnt; if (oc > OVF_MAX) oc = OVF_MAX;
        for (int i = 0; i < oc; ++i) {
            int2 e = ovf[i];
            #pragma unroll
            for (int r = 0; r < 4; ++r) {
                if (deg[r] > CAP && e.y == m0 + r) {
                    float wq = rsqrtf(1.0f + (float)fillc[e.x]);
                    unsigned pp = h32[(size_t)e.x * 64 + l];
                    ax[r] = fmaf(wq, bflo2f(pp), ax[r]);
                    ay[r] = fmaf(wq, bfhi2f(pp), ay[r]);
                }
            }
        }
    }
    #pragma unroll
    for (int r = 0; r < 4; ++r) {
        int n = m0 + r;
        float di = rsqrtf(1.0f + (float)deg[r]);
        float di2 = di * di;
        float ox = fmaf(di2, bflo2f(ps[r]), di * ax[r]) + bb.x;
        float oy = fmaf(di2, bfhi2f(ps[r]), di * ay[r]) + bb.y;
        ox = fmaxf(ox, 0.f); oy = fmaxf(oy, 0.f);           // relu (layer 1)
        unsigned po = (n < N) ? ((unsigned)f2bf(ox) | ((unsigned)f2bf(oy) << 16)) : 0u;
        *reinterpret_cast<unsigned*>(&agg[w * 4 + r][l * 2]) = po;
    }
    __syncthreads();

    int lr = l & 15, lg = l >> 4;
    f32x4 acc[2] = {};
    #pragma unroll
    for (int kk = 0; kk < 4; ++kk) {
        bf16x8v af = *reinterpret_cast<const bf16x8v*>(&agg[lr][kk * 32 + lg * 8]);
        #pragma unroll
        for (int j = 0; j < 2; ++j) {
            int nt = w * 2 + j;
            bf16x8v bfrag = *reinterpret_cast<const bf16x8v*>(&Wl[nt * 16 + lr][kk * 32 + lg * 8]);
            acc[j] = __builtin_amdgcn_mfma_f32_16x16x32_bf16(af, bfrag, acc[j], 0, 0, 0);
        }
    }
    int mb = blockIdx.x * 16;
    #pragma unroll
    for (int j = 0; j < 2; ++j) {
        int nt = w * 2 + j;
        #pragma unroll
        for (int r4 = 0; r4 < 4; ++r4) {
            int rr = mb + lg * 4 + r4;
            if (rr < N) hA2[(size_t)rr * DD + nt * 16 + lr] = f2bf(acc[j][r4]);
        }
    }
}

// ---- D5: padded-CSR gather (layer 2 out): f32 out + bf2, no relu ----
__global__ __launch_bounds__(256) void k_gather_pad(const int* __restrict__ fillc, const int* __restrict__ srcp,
                                                    const unsigned* __restrict__ h32,
                                                    const float* __restrict__ bias, float* __restrict__ outp,
                                                    int N, const int* __restrict__ ovfcnt, const int2* __restrict__ ovf) {
    int l = threadIdx.x & 63;
    int g = blockIdx.x * 4 + (threadIdx.x >> 6);
    int m0 = g * 4;
    if (m0 >= N) return;
    float2 bb = reinterpret_cast<const float2*>(bias)[l];

    int fcidx = m0 + l; if (fcidx >= N) fcidx = N - 1;
    int fc = (l < 4) ? fillc[fcidx] : 0;

    int deg[4], c[4], sv[4], wvb[4];
    #pragma unroll
    for (int r = 0; r < 4; ++r) {
        deg[r] = __builtin_amdgcn_readlane(fc, r);
        int cc = deg[r] > CAP ? CAP : deg[r];
        c[r] = cc;
        int row = (m0 + r < N) ? (m0 + r) : (N - 1);
        sv[r] = (cc > 0) ? srcp[(size_t)row * CAP + (l < cc ? l : cc - 1)] : 0;
    }
    #pragma unroll
    for (int r = 0; r < 4; ++r)
        wvb[r] = __builtin_bit_cast(int, rsqrtf(1.0f + (float)fillc[sv[r]]));

    unsigned p[4][8]; float w[4][8];
    #pragma unroll
    for (int r = 0; r < 4; ++r) {
        int f = c[r] < 8 ? c[r] : 8;
        #pragma unroll
        for (int q = 0; q < 8; ++q) {
            int i = (q < f) ? q : (f > 0 ? f - 1 : 0);
            int s = __builtin_amdgcn_readlane(sv[r], i);
            p[r][q] = h32[(size_t)s * 64 + l];
            w[r][q] = (q < f) ? rl_f(wvb[r], i) : 0.f;
        }
    }
    unsigned ps[4];
    #pragma unroll
    for (int r = 0; r < 4; ++r) {
        int n = m0 + r; int nc = n < N ? n : N - 1;
        ps[r] = h32[(size_t)nc * 64 + l];
    }

    float ax[4] = {0.f, 0.f, 0.f, 0.f}, ay[4] = {0.f, 0.f, 0.f, 0.f};
    #pragma unroll
    for (int r = 0; r < 4; ++r)
        #pragma unroll
        for (int q = 0; q < 8; ++q) {
            ax[r] = fmaf(w[r][q], bflo2f(p[r][q]), ax[r]);
            ay[r] = fmaf(w[r][q], bfhi2f(p[r][q]), ay[r]);
        }
    #pragma unroll
    for (int r = 0; r < 4; ++r) {
        for (int i = 8; i < c[r]; i += 8) {
            #pragma unroll
            for (int q = 0; q < 8; ++q) {
                int ii = (i + q < c[r]) ? i + q : c[r] - 1;
                int s = __builtin_amdgcn_readlane(sv[r], ii);
                unsigned pp = h32[(size_t)s * 64 + l];
                float wq = (i + q < c[r]) ? rl_f(wvb[r], ii) : 0.f;
                ax[r] = fmaf(wq, bflo2f(pp), ax[r]);
                ay[r] = fmaf(wq, bfhi2f(pp), ay[r]);
            }
        }
    }
    int anyovf = 0;
    #pragma unroll
    for (int r = 0; r < 4; ++r) anyovf |= (deg[r] > CAP) ? 1 : 0;
    if (anyovf) {
        int oc = *ovfcnt; if (oc > OVF_MAX) oc = OVF_MAX;
        for (int i = 0; i < oc; ++i) {
            int2 e = ovf[i];
            #pragma unroll
            for (int r = 0; r < 4; ++r) {
                if (deg[r] > CAP && e.y == m0 + r) {
                    float wq = rsqrtf(1.0f + (float)fillc[e.x]);
                    unsigned pp = h32[(size_t)e.x * 64 + l];
                    ax[r] = fmaf(wq, bflo2f(pp), ax[r]);
                    ay[r] = fmaf(wq, bfhi2f(pp), ay[r]);
                }
            }
        }
    }
    #pragma unroll
    for (int r = 0; r < 4; ++r) {
        int n = m0 + r;
        if (n < N) {
            float di = rsqrtf(1.0f + (float)deg[r]);
            float di2 = di * di;
            float ox = fmaf(di2, bflo2f(ps[r]), di * ax[r]) + bb.x;
            float oy = fmaf(di2, bfhi2f(ps[r]), di * ay[r]) + bb.y;
            reinterpret_cast<float2*>(outp)[(size_t)n * 64 + l] = make_float2(ox, oy);
        }
    }
}

extern "C" void kernel_launch(void* const* d_in, const int* in_sizes, int n_in,
                              void* d_out, int out_size, void* d_ws, size_t ws_size,
                              hipStream_t stream) {
    const float* x  = (const float*)d_in[0];
    const int*   ei = (const int*)d_in[1];
    const float* W1 = (const float*)d_in[2];
    const float* b1 = (const float*)d_in[3];
    const float* W2 = (const float*)d_in[4];
    const float* b2 = (const float*)d_in[5];
    // Wq/bq/Wk/bk (6..9) dead: softmax over seq_len=1 is identity.
    const float* Wv = (const float*)d_in[10];
    const float* bv = (const float*)d_in[11];
    const float* Wo = (const float*)d_in[12];
    const float* bo = (const float*)d_in[13];
    int N = in_sizes[0] / DD;
    int E = in_sizes[1] / 2;
    const int* src = ei;
    const int* dst = ei + E;
    float* out = (float*)d_out;

    unsigned* hA  = (unsigned*)d_ws;                  // N*64 u32 (gemm1 out, bf16)
    unsigned* hA2 = hA + (size_t)N * 64;              // N*64 u32 (fused out, bf16)
    float* Wf     = (float*)(hA2 + (size_t)N * 64);   // 128*128 f32
    float* bfo    = Wf + DD * DD;                     // 128
    float* bf2    = bfo + DD;                         // 128
    unsigned short* Wt1  = (unsigned short*)(bf2 + DD);   // 128*128 bf16
    unsigned short* W2ft = Wt1 + DD * DD;                 // 128*128 bf16
    int* fillc  = (int*)(W2ft + DD * DD);             // N (+1 for ovfcnt)
    int* ovfcnt = fillc + N;                          // 1
    int2* ovf   = (int2*)(((uintptr_t)(ovfcnt + 1) + 63) & ~(uintptr_t)63);   // OVF_MAX
    int* srcp   = (int*)(((uintptr_t)(ovf + OVF_MAX) + 63) & ~(uintptr_t)63); // N*CAP, 64B-aligned

    int nchunks = (E + ECHUNK - 1) / ECHUNK;
    int FB = nchunks * 8;   // 8 XCD bins per edge chunk
    int ZB = 512;

    // D1: zero fillc || Wf fold || Wt1 transpose (all independent)
    k_prep1<<<ZB + 65 + 64, 256, 0, stream>>>(fillc, N, ZB, Wv, Wo, bv, bo, Wf, bfo, W1, Wt1);
    // D2: XCD-local padded fill || W2ft/bf2 (needs Wf)
    k_fill_wprep<<<FB + 65, 256, 0, stream>>>(src, dst, fillc, srcp, ovfcnt, ovf, E, N, FB,
                                              W2, Wf, b2, bfo, W2ft, bf2);
    // D3: layer-1 GEMM: hA = bf16(x @ W1)
    k_gemm_mfma<<<512, 256, 0, stream>>>(x, Wt1, (unsigned short*)hA, N);
    // D4: FUSED gather1+gemm2: hA2 = bf16( relu(G(hA)+b1) @ W2f )
    int ggb = (N + 15) / 16;
    k_gg<<<ggb, 256, 0, stream>>>(fillc, srcp, hA, b1, W2ft, (unsigned short*)hA2, N, ovfcnt, ovf);
    // D5: gather layer 2 -> out (f32, +bf2)
    int gb = ((N + 3) / 4 + 3) / 4;
    k_gather_pad<<<gb, 256, 0, stream>>>(fillc, srcp, hA2, bf2, out, N, ovfcnt, ovf);
}